// Round 14
// baseline (1116.444 us; speedup 1.0000x reference)
//
#include <hip/hip_runtime.h>
#include <float.h>
#include <stdint.h>

#define IN_DIM 1433
#define HID 16
#define OUTD 7

#define KT 64        // k-tile width (floats)
#define NTT 23       // tiles: 22 full + tail; tail kt = 25 - h

#define AS1 __attribute__((address_space(1)))
#define AS3 __attribute__((address_space(3)))

// ---------------- GEMM1: xw1[N][16] = feat[N][1433] @ W1[1433][16] -------------
// Page-compact DMA gemm. 256 threads = 4 waves; wave w owns the 64 rows
// R = row0 + 4*l + w (class w) -> alignment phase h=(4-w)&3 is wave-uniform,
// W1 indices are wave-uniform (s_load, vmcnt-silent compute) [R13-proven].
// NEW vs R13: each DMA instr covers 4 rows x 256 B = 4 CONSECUTIVE lines per
// DRAM page (vs 16 rows x 64 B = 1 line/page). Page-hit bursts cut effective
// latency; per-lane source is XOR-permuted at 16B granularity WITHIN each
// row's 256B run (same page region -> page burst preserved; read-side XOR
// bounds LDS conflicts to ~8-way, hidden under FMA).
// Ring-2 per-wave-private buffers, barrier-free, s_waitcnt vmcnt(16).
__global__ __launch_bounds__(256, 1) void gemm1_kernel(
    const float* __restrict__ feat, const float* __restrict__ W1,
    float* __restrict__ xw1, int N)
{
    __shared__ float xs[4][2][64 * KT];   // 4 waves x 2 bufs x 16 KB = 128 KB
    const int t = threadIdx.x;
    const int l = t & 63;
    const int w = t >> 6;
    const int row0 = blockIdx.x * 256;
    const int h = __builtin_amdgcn_readfirstlane((4 - w) & 3);
    const long maxBase = (long)N * IN_DIM - 4;

    const int R = row0 + 4 * l + w;       // compute/output row of this thread

    // staging decomposition: lane = (sub-row 0..3) x (16B block 0..15)
    const int sub = l >> 4;
    const int ib  = l & 15;
    const long rowterm = (long)(row0 + 4 * sub + w) * IN_DIM + h;

    float acc[16];
#pragma unroll
    for (int j = 0; j < 16; ++j) acc[j] = 0.f;

    // head: k = 0..h-1 (scalar, before the aligned window)
    for (int k = 0; k < h; ++k) {
        const float x = (R < N) ? feat[(long)R * IN_DIM + k] : 0.f;
        const float* wr = W1 + k * HID;
#pragma unroll
        for (int j = 0; j < 16; ++j) acc[j] += x * wr[j];
    }
    asm volatile("s_waitcnt vmcnt(0)" ::: "memory");   // drain head loads
    __builtin_amdgcn_sched_barrier(0);

    // stage one 64x64 tile: 16 instrs; instr j = rows 4j..4j+3, 256 B each,
    // block permuted by (rr&15) within the row's 256B run (page-compact).
    auto stage = [&](int buf, int tile) {
#pragma unroll
        for (int j = 0; j < 16; ++j) {
            const int rr = 4 * j + sub;
            long e = rowterm + (long)(16 * j) * IN_DIM + tile * KT
                     + 4 * (ib ^ (rr & 15));
            if (e > maxBase) e = maxBase;   // tail clamp (OOB rows / last tile)
            __builtin_amdgcn_global_load_lds(
                (const AS1 void*)(feat + e),
                (AS3 void*)(&xs[w][buf][(4 * j) * KT]), 16, 0, 0);
        }
    };

#define WAITVM(Nimm)                                                         \
    asm volatile("s_waitcnt vmcnt(" #Nimm ")" ::: "memory");                 \
    __builtin_amdgcn_sched_barrier(0);

    const int lx = l & 15;
    // full-tile compute: 16 float4-blocks = 64 k's; W via uniform s_load
#define COMP(buf, tile)                                                      \
    {                                                                        \
        const float* xrow = &xs[w][buf][l * KT];                             \
        const int kb0 = h + (tile) * KT;                                     \
        _Pragma("unroll")                                                    \
        for (int kb = 0; kb < 16; ++kb) {                                    \
            const float4 xv = *(const float4*)&xrow[((kb ^ lx) << 2)];       \
            const float* wk = W1 + (size_t)(kb0 + 4 * kb) * HID;             \
            _Pragma("unroll")                                                \
            for (int e = 0; e < 4; ++e) {                                    \
                const float xe = ((const float*)&xv)[e];                     \
                const float4 wA = *(const float4*)(wk + e * HID);            \
                const float4 wB = *(const float4*)(wk + e * HID + 4);        \
                const float4 wC = *(const float4*)(wk + e * HID + 8);        \
                const float4 wD = *(const float4*)(wk + e * HID + 12);       \
                acc[0]  += xe * wA.x; acc[1]  += xe * wA.y;                  \
                acc[2]  += xe * wA.z; acc[3]  += xe * wA.w;                  \
                acc[4]  += xe * wB.x; acc[5]  += xe * wB.y;                  \
                acc[6]  += xe * wB.z; acc[7]  += xe * wB.w;                  \
                acc[8]  += xe * wC.x; acc[9]  += xe * wC.y;                  \
                acc[10] += xe * wC.z; acc[11] += xe * wC.w;                  \
                acc[12] += xe * wD.x; acc[13] += xe * wD.y;                  \
                acc[14] += xe * wD.z; acc[15] += xe * wD.w;                  \
            }                                                                \
        }                                                                    \
    }

    stage(0, 0);
    stage(1, 1);                           // 32 DMA outstanding per wave
    for (int i = 0; i < 21; ++i) {         // tiles 0..20; stages 2..22
        WAITVM(16);                        // tile i resident; i+1 in flight
        COMP(i & 1, i);
        stage(i & 1, i + 2);
    }
    WAITVM(16);
    COMP(1, 21);                           // tile 21 (buf 1)
    WAITVM(0);
    {   // tile 22: kt = 25 - h valid k's (wave-uniform), buf 0
        const int kt = 25 - h;
        const int nb = kt >> 2, tl = kt & 3;
        const float* xrow = &xs[w][0][l * KT];
        const int kb0 = h + 22 * KT;
        for (int kb = 0; kb < nb; ++kb) {
            const float4 xv = *(const float4*)&xrow[((kb ^ lx) << 2)];
            const float* wk = W1 + (size_t)(kb0 + 4 * kb) * HID;
#pragma unroll
            for (int e = 0; e < 4; ++e) {
                const float xe = ((const float*)&xv)[e];
                const float* wr = wk + e * HID;
#pragma unroll
                for (int j = 0; j < 16; ++j) acc[j] += xe * wr[j];
            }
        }
        for (int kk = nb * 4; kk < nb * 4 + tl; ++kk) {
            const float x = xrow[(((kk >> 2) ^ lx) << 2) | (kk & 3)];
            const float* wr = W1 + (size_t)(kb0 + kk) * HID;
#pragma unroll
            for (int j = 0; j < 16; ++j) acc[j] += x * wr[j];
        }
    }
#undef COMP
#undef WAITVM

    if (R < N) {
        float4* o = (float4*)(xw1 + (size_t)R * HID);
        o[0] = make_float4(acc[0],  acc[1],  acc[2],  acc[3]);
        o[1] = make_float4(acc[4],  acc[5],  acc[6],  acc[7]);
        o[2] = make_float4(acc[8],  acc[9],  acc[10], acc[11]);
        o[3] = make_float4(acc[12], acc[13], acc[14], acc[15]);
    }
}

// ---------------- CSR build: histogram -> scan -> counting-sort fill ----------
__global__ __launch_bounds__(256) void hist_kernel(
    const int* __restrict__ dst, int* __restrict__ cnt, int E)
{
    const int i4 = blockIdx.x * 256 + threadIdx.x;
    const int e0 = i4 * 4;
    if (e0 + 3 < E) {
        const int4 d = ((const int4*)dst)[i4];
        atomicAdd(&cnt[d.x], 1);
        atomicAdd(&cnt[d.y], 1);
        atomicAdd(&cnt[d.z], 1);
        atomicAdd(&cnt[d.w], 1);
    } else {
        for (int e = e0; e < E; ++e) atomicAdd(&cnt[dst[e]], 1);
    }
}

__global__ __launch_bounds__(256) void scan1_kernel(
    const int* __restrict__ cnt, int* __restrict__ offs,
    int* __restrict__ bsum, int N)
{
    __shared__ int lds[256];
    const int t = threadIdx.x, b = blockIdx.x;
    const int base = b * 1024 + t * 4;
    int c0 = 0, c1 = 0, c2 = 0, c3 = 0;
    if (base + 0 < N) c0 = cnt[base + 0];
    if (base + 1 < N) c1 = cnt[base + 1];
    if (base + 2 < N) c2 = cnt[base + 2];
    if (base + 3 < N) c3 = cnt[base + 3];
    const int s = c0 + c1 + c2 + c3;
    lds[t] = s;
    __syncthreads();
    for (int off = 1; off < 256; off <<= 1) {
        int v = (t >= off) ? lds[t - off] : 0;
        __syncthreads();
        lds[t] += v;
        __syncthreads();
    }
    const int excl = lds[t] - s;
    if (t == 255) bsum[b] = lds[255];
    int run = excl;
    if (base + 0 < N) { offs[base + 0] = run; run += c0; }
    if (base + 1 < N) { offs[base + 1] = run; run += c1; }
    if (base + 2 < N) { offs[base + 2] = run; run += c2; }
    if (base + 3 < N) { offs[base + 3] = run; run += c3; }
}

__global__ __launch_bounds__(256) void scan2_kernel(
    const int* __restrict__ bsum, int* __restrict__ bbase, int NB)
{
    __shared__ int lds[256];
    const int t = threadIdx.x;
    const int v = (t < NB) ? bsum[t] : 0;
    lds[t] = v;
    __syncthreads();
    for (int off = 1; off < 256; off <<= 1) {
        int u = (t >= off) ? lds[t - off] : 0;
        __syncthreads();
        lds[t] += u;
        __syncthreads();
    }
    bbase[t] = lds[t] - v;
}

__global__ __launch_bounds__(256) void scan3_kernel(
    int* __restrict__ offs, int* __restrict__ cursor,
    const int* __restrict__ bbase, int N, int E)
{
    const int t = threadIdx.x, b = blockIdx.x;
    const int add = bbase[b];
    const int base = b * 1024 + t * 4;
#pragma unroll
    for (int i = 0; i < 4; ++i) {
        const int idx = base + i;
        if (idx < N) {
            const int v = offs[idx] + add;
            offs[idx] = v;
            cursor[idx] = v;
        }
    }
    if (b == 0 && t == 0) offs[N] = E;
}

__global__ __launch_bounds__(256) void fill_kernel(
    const int* __restrict__ src, const int* __restrict__ dst,
    const float* __restrict__ a, int* __restrict__ cursor,
    uint2* __restrict__ pairs, int E)
{
    const int i4 = blockIdx.x * 256 + threadIdx.x;
    const int e0 = i4 * 4;
    if (e0 + 3 < E) {
        const int4   s4 = ((const int4*)src)[i4];
        const int4   d4 = ((const int4*)dst)[i4];
        const float4 a4 = ((const float4*)a)[i4];
        int p0 = atomicAdd(&cursor[d4.x], 1);
        pairs[p0] = make_uint2((unsigned)s4.x, __float_as_uint(a4.x));
        int p1 = atomicAdd(&cursor[d4.y], 1);
        pairs[p1] = make_uint2((unsigned)s4.y, __float_as_uint(a4.y));
        int p2 = atomicAdd(&cursor[d4.z], 1);
        pairs[p2] = make_uint2((unsigned)s4.z, __float_as_uint(a4.z));
        int p3 = atomicAdd(&cursor[d4.w], 1);
        pairs[p3] = make_uint2((unsigned)s4.w, __float_as_uint(a4.w));
    } else {
        for (int e = e0; e < E; ++e) {
            const int pos = atomicAdd(&cursor[dst[e]], 1);
            pairs[pos] = make_uint2((unsigned)src[e], __float_as_uint(a[e]));
        }
    }
}

// ------- gather1: agg = sum(a*xw1[src]) ; fused h=relu(agg+b1); xw2 = h@W2 ----
__global__ __launch_bounds__(256) void gather1_kernel(
    const uint2* __restrict__ pairs, const int* __restrict__ offs,
    const float* __restrict__ xw1, const float* __restrict__ b1,
    const float* __restrict__ W2, float* __restrict__ xw2, int N)
{
    __shared__ float w2s[HID * OUTD];
    const int t = threadIdx.x;
    if (t < HID * OUTD) w2s[t] = W2[t];
    __syncthreads();
    const int lane = t & 63;
    const int r = blockIdx.x * 4 + (t >> 6);
    if (r >= N) return;
    const int g = lane >> 2;
    const int c = lane & 3;
    const int start = offs[r], end = offs[r + 1];
    float4 acc = make_float4(0.f, 0.f, 0.f, 0.f);
    int e = start + g;
    for (; e + 16 < end; e += 32) {
        const uint2 p0 = pairs[e];
        const uint2 p1 = pairs[e + 16];
        const float4 v0 = *(const float4*)(xw1 + (size_t)p0.x * HID + c * 4);
        const float4 v1 = *(const float4*)(xw1 + (size_t)p1.x * HID + c * 4);
        const float a0 = __uint_as_float(p0.y);
        const float a1 = __uint_as_float(p1.y);
        acc.x += a0 * v0.x + a1 * v1.x;
        acc.y += a0 * v0.y + a1 * v1.y;
        acc.z += a0 * v0.z + a1 * v1.z;
        acc.w += a0 * v0.w + a1 * v1.w;
    }
    if (e < end) {
        const uint2 p0 = pairs[e];
        const float4 v0 = *(const float4*)(xw1 + (size_t)p0.x * HID + c * 4);
        const float a0 = __uint_as_float(p0.y);
        acc.x += a0 * v0.x; acc.y += a0 * v0.y;
        acc.z += a0 * v0.z; acc.w += a0 * v0.w;
    }
#pragma unroll
    for (int m = 4; m < 64; m <<= 1) {
        acc.x += __shfl_xor(acc.x, m);
        acc.y += __shfl_xor(acc.y, m);
        acc.z += __shfl_xor(acc.z, m);
        acc.w += __shfl_xor(acc.w, m);
    }
    const float4 b1v = ((const float4*)b1)[c];
    float4 hv;
    hv.x = fmaxf(acc.x + b1v.x, 0.f);
    hv.y = fmaxf(acc.y + b1v.y, 0.f);
    hv.z = fmaxf(acc.z + b1v.z, 0.f);
    hv.w = fmaxf(acc.w + b1v.w, 0.f);
    float hh[16];
#pragma unroll
    for (int cc = 0; cc < 4; ++cc) {
        hh[cc * 4 + 0] = __shfl(hv.x, cc);
        hh[cc * 4 + 1] = __shfl(hv.y, cc);
        hh[cc * 4 + 2] = __shfl(hv.z, cc);
        hh[cc * 4 + 3] = __shfl(hv.w, cc);
    }
    const int col = (lane & 7) < OUTD ? (lane & 7) : 0;
    float sacc = 0.f;
#pragma unroll
    for (int j = 0; j < HID; ++j) sacc += hh[j] * w2s[j * OUTD + col];
    if (lane < 8) xw2[(size_t)r * 8 + lane] = (lane < OUTD) ? sacc : 0.f;
}

// ------- gather2: o = sum(a*xw2[src]) + b2 ; fused log_softmax -> out ---------
__global__ __launch_bounds__(256) void gather2_kernel(
    const uint2* __restrict__ pairs, const int* __restrict__ offs,
    const float* __restrict__ xw2, const float* __restrict__ b2,
    float* __restrict__ out, int N)
{
    const int t = threadIdx.x;
    const int lane = t & 63;
    const int r = blockIdx.x * 4 + (t >> 6);
    if (r >= N) return;
    const int g = lane >> 1;
    const int c = lane & 1;
    const int start = offs[r], end = offs[r + 1];
    float4 acc = make_float4(0.f, 0.f, 0.f, 0.f);
    for (int e = start + g; e < end; e += 32) {
        const uint2 p = pairs[e];
        const float4 v = *(const float4*)(xw2 + (size_t)p.x * 8 + c * 4);
        const float a = __uint_as_float(p.y);
        acc.x += a * v.x; acc.y += a * v.y;
        acc.z += a * v.z; acc.w += a * v.w;
    }
#pragma unroll
    for (int m = 2; m < 64; m <<= 1) {
        acc.x += __shfl_xor(acc.x, m);
        acc.y += __shfl_xor(acc.y, m);
        acc.z += __shfl_xor(acc.z, m);
        acc.w += __shfl_xor(acc.w, m);
    }
    float4 x;
    if (c == 0) {
        const float4 b2v = *(const float4*)b2;
        x.x = acc.x + b2v.x; x.y = acc.y + b2v.y;
        x.z = acc.z + b2v.z; x.w = acc.w + b2v.w;
    } else {
        x.x = acc.x + b2[4]; x.y = acc.y + b2[5];
        x.z = acc.z + b2[6]; x.w = -FLT_MAX;
    }
    float mymax = fmaxf(fmaxf(x.x, x.y), x.z);
    if (c == 0) mymax = fmaxf(mymax, x.w);
    const float m = fmaxf(mymax, __shfl_xor(mymax, 1));
    float es = expf(x.x - m) + expf(x.y - m) + expf(x.z - m);
    if (c == 0) es += expf(x.w - m);
    const float s = es + __shfl_xor(es, 1);
    const float lg = logf(s);
    float* op = out + (size_t)r * OUTD;
    if (c == 0) {
        op[0] = x.x - m - lg; op[1] = x.y - m - lg;
        op[2] = x.z - m - lg; op[3] = x.w - m - lg;
    } else {
        op[4] = x.x - m - lg; op[5] = x.y - m - lg;
        op[6] = x.z - m - lg;
    }
}

extern "C" void kernel_launch(void* const* d_in, const int* in_sizes, int n_in,
                              void* d_out, int out_size, void* d_ws, size_t ws_size,
                              hipStream_t stream)
{
    const float* feat  = (const float*)d_in[0];
    const int*   esrc  = (const int*)d_in[1];
    const int*   edst  = (const int*)d_in[2];
    const float* avals = (const float*)d_in[3];
    const float* W1    = (const float*)d_in[4];
    const float* b1    = (const float*)d_in[5];
    const float* W2    = (const float*)d_in[6];
    const float* b2    = (const float*)d_in[7];
    float* out = (float*)d_out;

    const int N = in_sizes[0] / IN_DIM;   // 150000
    const int E = in_sizes[1];            // 4800000
    const int NB = (N + 1023) / 1024;     // 147 (<=256 for scan2)

    // workspace layout
    char* p = (char*)d_ws;
    float* xw1   = (float*)p; p += (size_t)N * HID * sizeof(float);
    float* xw2   = (float*)p; p += (size_t)N * 8 * sizeof(float);
    int*   cnt   = (int*)p;   p += (size_t)N * sizeof(int);
    int*   offs  = (int*)p;   p += (size_t)(N + 1) * sizeof(int);
    int*   cursor= (int*)p;   p += (size_t)N * sizeof(int);
    int*   bsum  = (int*)p;   p += 256 * sizeof(int);
    int*   bbase = (int*)p;   p += 256 * sizeof(int);
    p = (char*)(((uintptr_t)p + 15) & ~(uintptr_t)15);
    uint2* pairs = (uint2*)p;

    hipMemsetAsync(cnt, 0, (size_t)N * sizeof(int), stream);

    gemm1_kernel<<<(N + 255) / 256, 256, 0, stream>>>(feat, W1, xw1, N);

    {
        const int n4 = (E + 3) / 4;
        hist_kernel<<<(n4 + 255) / 256, 256, 0, stream>>>(edst, cnt, E);
    }
    scan1_kernel<<<NB, 256, 0, stream>>>(cnt, offs, bsum, N);
    scan2_kernel<<<1, 256, 0, stream>>>(bsum, bbase, NB);
    scan3_kernel<<<NB, 256, 0, stream>>>(offs, cursor, bbase, N, E);
    {
        const int n4 = (E + 3) / 4;
        fill_kernel<<<(n4 + 255) / 256, 256, 0, stream>>>(esrc, edst, avals, cursor, pairs, E);
    }

    gather1_kernel<<<(N + 3) / 4, 256, 0, stream>>>(pairs, offs, xw1, b1, W2, xw2, N);
    gather2_kernel<<<(N + 3) / 4, 256, 0, stream>>>(pairs, offs, xw2, b2, out, N);
}

// Round 15
// 973.022 us; speedup vs baseline: 1.1474x; 1.1474x over previous
//
#include <hip/hip_runtime.h>
#include <float.h>
#include <stdint.h>

#define IN_DIM 1433
#define HID 16
#define OUTD 7

#define AS1 __attribute__((address_space(1)))
#define AS3 __attribute__((address_space(3)))

// ---------------- GEMM1: xw1[N][16] = feat[N][1433] @ W1[1433][16] -------------
// K-split twin of R13 (the best structure measured: aligned width-16 DMA,
// wave-uniform class -> scalar W1 loads, wave-private ring-2, barrier-free).
// R13's limit was total parallelism (2344 waves = 9.2/CU). Here each 256-row
// panel is handled by 8 waves: wave (c, hf) = class-c rows, k-half hf:
//   half 0: k in [0, s_c)      (head [0,h) scalar + 44 tiles + 12-float part)
//   half 1: k in [s_c, 1433)   (44 tiles + (13-h)-float partial)
// s_c = 716 + h keeps both halves 16B-aligned (h = (4-c)&3, c = row%4 class).
// 4688 waves -> 16 waves/CU (2 blocks x 64KB LDS). One __syncthreads at the
// end merges the two acc[16] halves via LDS.
__global__ __launch_bounds__(512, 4) void gemm1_kernel(
    const float* __restrict__ feat, const float* __restrict__ W1,
    float* __restrict__ xw1, int N)
{
    __shared__ float xs[8][2][64 * 16];   // 8 waves x 2 bufs x 4 KB = 64 KB
    const int t = threadIdx.x;
    const int l = t & 63;
    const int w = __builtin_amdgcn_readfirstlane(t >> 6);   // wave 0..7
    const int c  = w & 3;                 // alignment class
    const int hf = w >> 2;                // k-half
    const int row0 = blockIdx.x * 256;
    const int R = row0 + 4 * l + c;       // this thread's row
    const long maxBase = (long)N * IN_DIM - 4;

    const int h    = (4 - c) & 3;         // aligned window start for class c
    const int sc   = 716 + h;             // split point (aligned for class c)
    const int kbeg = hf ? sc : h;         // this wave's aligned k-origin
    const int rem  = hf ? (13 - h) : 12;  // valid floats in partial tile 44
    const int nb   = rem >> 2;
    const int tl   = rem & 3;

    // per-lane DMA source bases (tile 0): instr j = rows 16j..16j+15, 64B each;
    // granule slot (l&3) of row rc holds logical block (l&3)^(rc&3) [rule #21]
    long src[4];
#pragma unroll
    for (int j = 0; j < 4; ++j) {
        const int rc = j * 16 + (l >> 2);
        const int bs = (l & 3) ^ (rc & 3);
        src[j] = (long)(row0 + 4 * rc + c) * IN_DIM + kbeg + 4 * bs;
    }

    float acc[16];
#pragma unroll
    for (int j = 0; j < 16; ++j) acc[j] = 0.f;

    // head (half 0 only): k = 0..h-1 scalar
    if (hf == 0) {
        for (int k = 0; k < h; ++k) {
            const float x = (R < N) ? feat[(long)R * IN_DIM + k] : 0.f;
            const float* wr = W1 + k * HID;
#pragma unroll
            for (int j = 0; j < 16; ++j) acc[j] += x * wr[j];
        }
    }
    asm volatile("s_waitcnt vmcnt(0)" ::: "memory");
    __builtin_amdgcn_sched_barrier(0);

    // stage tile i (16 k's x 64 rows = 4KB): 4 width-16 DMA instrs
    auto stage = [&](int buf, int tile) {
#pragma unroll
        for (int j = 0; j < 4; ++j) {
            long e = src[j] + 16 * tile;
            if (e > maxBase) e = maxBase;   // absolute-OOB clamp only
            __builtin_amdgcn_global_load_lds(
                (const AS1 void*)(feat + e),
                (AS3 void*)(&xs[w][buf][j * 256]), 16, 0, 0);
        }
    };

#define WAITVM(Nimm)                                                         \
    asm volatile("s_waitcnt vmcnt(" #Nimm ")" ::: "memory");                 \
    __builtin_amdgcn_sched_barrier(0);

    const int lx = l & 3;
#define COMP_FULL(buf, i)                                                    \
    {                                                                        \
        const float* xrow = &xs[w][buf][l * 16];                             \
        const int kb0 = kbeg + 16 * (i);                                     \
        _Pragma("unroll")                                                    \
        for (int b = 0; b < 4; ++b) {                                        \
            const float4 xv = *(const float4*)&xrow[((b ^ lx) << 2)];        \
            const float* wk = W1 + (size_t)(kb0 + 4 * b) * HID;              \
            _Pragma("unroll")                                                \
            for (int e = 0; e < 4; ++e) {                                    \
                const float xe = ((const float*)&xv)[e];                     \
                const float4 wA = *(const float4*)(wk + e * HID);            \
                const float4 wB = *(const float4*)(wk + e * HID + 4);        \
                const float4 wC = *(const float4*)(wk + e * HID + 8);        \
                const float4 wD = *(const float4*)(wk + e * HID + 12);       \
                acc[0]  += xe * wA.x; acc[1]  += xe * wA.y;                  \
                acc[2]  += xe * wA.z; acc[3]  += xe * wA.w;                  \
                acc[4]  += xe * wB.x; acc[5]  += xe * wB.y;                  \
                acc[6]  += xe * wB.z; acc[7]  += xe * wB.w;                  \
                acc[8]  += xe * wC.x; acc[9]  += xe * wC.y;                  \
                acc[10] += xe * wC.z; acc[11] += xe * wC.w;                  \
                acc[12] += xe * wD.x; acc[13] += xe * wD.y;                  \
                acc[14] += xe * wD.z; acc[15] += xe * wD.w;                  \
            }                                                                \
        }                                                                    \
    }

    // 45 tiles: 0..43 full, 44 partial (rem floats). Ring-2, vmcnt-counted.
    stage(0, 0);
    stage(1, 1);
    for (int i = 0; i < 43; ++i) {         // compute 0..42, stage 2..44
        WAITVM(4);
        COMP_FULL(i & 1, i);
        stage(i & 1, i + 2);
    }
    WAITVM(4);
    COMP_FULL(1, 43);                      // tile 43 (buf 1)
    WAITVM(0);
    {   // tile 44 partial (buf 0): nb float4-blocks + tl scalars
        const float* xrow = &xs[w][0][l * 16];
        const int kb0 = kbeg + 704;
        for (int b = 0; b < nb; ++b) {
            const float4 xv = *(const float4*)&xrow[((b ^ lx) << 2)];
            const float* wk = W1 + (size_t)(kb0 + 4 * b) * HID;
#pragma unroll
            for (int e = 0; e < 4; ++e) {
                const float xe = ((const float*)&xv)[e];
                const float* wr = wk + e * HID;
#pragma unroll
                for (int j = 0; j < 16; ++j) acc[j] += xe * wr[j];
            }
        }
        for (int kk = nb * 4; kk < nb * 4 + tl; ++kk) {
            const float x = xrow[(((kk >> 2) ^ lx) << 2) | (kk & 3)];
            const float* wr = W1 + (size_t)(kb0 + kk) * HID;
#pragma unroll
            for (int j = 0; j < 16; ++j) acc[j] += x * wr[j];
        }
    }
#undef COMP_FULL
#undef WAITVM

    // merge halves: half1 -> LDS, half0 adds and stores
    if (hf == 1) {
        float* s = &xs[w][0][l * 16];
#pragma unroll
        for (int j = 0; j < 16; ++j) s[j] = acc[j];
    }
    __syncthreads();
    if (hf == 0) {
        const float* s = &xs[w + 4][0][l * 16];
#pragma unroll
        for (int j = 0; j < 16; ++j) acc[j] += s[j];
        if (R < N) {
            float4* o = (float4*)(xw1 + (size_t)R * HID);
            o[0] = make_float4(acc[0],  acc[1],  acc[2],  acc[3]);
            o[1] = make_float4(acc[4],  acc[5],  acc[6],  acc[7]);
            o[2] = make_float4(acc[8],  acc[9],  acc[10], acc[11]);
            o[3] = make_float4(acc[12], acc[13], acc[14], acc[15]);
        }
    }
}

// ---------------- CSR build: histogram -> scan -> counting-sort fill ----------
__global__ __launch_bounds__(256) void hist_kernel(
    const int* __restrict__ dst, int* __restrict__ cnt, int E)
{
    const int i4 = blockIdx.x * 256 + threadIdx.x;
    const int e0 = i4 * 4;
    if (e0 + 3 < E) {
        const int4 d = ((const int4*)dst)[i4];
        atomicAdd(&cnt[d.x], 1);
        atomicAdd(&cnt[d.y], 1);
        atomicAdd(&cnt[d.z], 1);
        atomicAdd(&cnt[d.w], 1);
    } else {
        for (int e = e0; e < E; ++e) atomicAdd(&cnt[dst[e]], 1);
    }
}

__global__ __launch_bounds__(256) void scan1_kernel(
    const int* __restrict__ cnt, int* __restrict__ offs,
    int* __restrict__ bsum, int N)
{
    __shared__ int lds[256];
    const int t = threadIdx.x, b = blockIdx.x;
    const int base = b * 1024 + t * 4;
    int c0 = 0, c1 = 0, c2 = 0, c3 = 0;
    if (base + 0 < N) c0 = cnt[base + 0];
    if (base + 1 < N) c1 = cnt[base + 1];
    if (base + 2 < N) c2 = cnt[base + 2];
    if (base + 3 < N) c3 = cnt[base + 3];
    const int s = c0 + c1 + c2 + c3;
    lds[t] = s;
    __syncthreads();
    for (int off = 1; off < 256; off <<= 1) {
        int v = (t >= off) ? lds[t - off] : 0;
        __syncthreads();
        lds[t] += v;
        __syncthreads();
    }
    const int excl = lds[t] - s;
    if (t == 255) bsum[b] = lds[255];
    int run = excl;
    if (base + 0 < N) { offs[base + 0] = run; run += c0; }
    if (base + 1 < N) { offs[base + 1] = run; run += c1; }
    if (base + 2 < N) { offs[base + 2] = run; run += c2; }
    if (base + 3 < N) { offs[base + 3] = run; run += c3; }
}

__global__ __launch_bounds__(256) void scan2_kernel(
    const int* __restrict__ bsum, int* __restrict__ bbase, int NB)
{
    __shared__ int lds[256];
    const int t = threadIdx.x;
    const int v = (t < NB) ? bsum[t] : 0;
    lds[t] = v;
    __syncthreads();
    for (int off = 1; off < 256; off <<= 1) {
        int u = (t >= off) ? lds[t - off] : 0;
        __syncthreads();
        lds[t] += u;
        __syncthreads();
    }
    bbase[t] = lds[t] - v;
}

__global__ __launch_bounds__(256) void scan3_kernel(
    int* __restrict__ offs, int* __restrict__ cursor,
    const int* __restrict__ bbase, int N, int E)
{
    const int t = threadIdx.x, b = blockIdx.x;
    const int add = bbase[b];
    const int base = b * 1024 + t * 4;
#pragma unroll
    for (int i = 0; i < 4; ++i) {
        const int idx = base + i;
        if (idx < N) {
            const int v = offs[idx] + add;
            offs[idx] = v;
            cursor[idx] = v;
        }
    }
    if (b == 0 && t == 0) offs[N] = E;
}

__global__ __launch_bounds__(256) void fill_kernel(
    const int* __restrict__ src, const int* __restrict__ dst,
    const float* __restrict__ a, int* __restrict__ cursor,
    uint2* __restrict__ pairs, int E)
{
    const int i4 = blockIdx.x * 256 + threadIdx.x;
    const int e0 = i4 * 4;
    if (e0 + 3 < E) {
        const int4   s4 = ((const int4*)src)[i4];
        const int4   d4 = ((const int4*)dst)[i4];
        const float4 a4 = ((const float4*)a)[i4];
        int p0 = atomicAdd(&cursor[d4.x], 1);
        pairs[p0] = make_uint2((unsigned)s4.x, __float_as_uint(a4.x));
        int p1 = atomicAdd(&cursor[d4.y], 1);
        pairs[p1] = make_uint2((unsigned)s4.y, __float_as_uint(a4.y));
        int p2 = atomicAdd(&cursor[d4.z], 1);
        pairs[p2] = make_uint2((unsigned)s4.z, __float_as_uint(a4.z));
        int p3 = atomicAdd(&cursor[d4.w], 1);
        pairs[p3] = make_uint2((unsigned)s4.w, __float_as_uint(a4.w));
    } else {
        for (int e = e0; e < E; ++e) {
            const int pos = atomicAdd(&cursor[dst[e]], 1);
            pairs[pos] = make_uint2((unsigned)src[e], __float_as_uint(a[e]));
        }
    }
}

// ------- gather1: agg = sum(a*xw1[src]) ; fused h=relu(agg+b1); xw2 = h@W2 ----
__global__ __launch_bounds__(256) void gather1_kernel(
    const uint2* __restrict__ pairs, const int* __restrict__ offs,
    const float* __restrict__ xw1, const float* __restrict__ b1,
    const float* __restrict__ W2, float* __restrict__ xw2, int N)
{
    __shared__ float w2s[HID * OUTD];
    const int t = threadIdx.x;
    if (t < HID * OUTD) w2s[t] = W2[t];
    __syncthreads();
    const int lane = t & 63;
    const int r = blockIdx.x * 4 + (t >> 6);
    if (r >= N) return;
    const int g = lane >> 2;
    const int c = lane & 3;
    const int start = offs[r], end = offs[r + 1];
    float4 acc = make_float4(0.f, 0.f, 0.f, 0.f);
    int e = start + g;
    for (; e + 16 < end; e += 32) {
        const uint2 p0 = pairs[e];
        const uint2 p1 = pairs[e + 16];
        const float4 v0 = *(const float4*)(xw1 + (size_t)p0.x * HID + c * 4);
        const float4 v1 = *(const float4*)(xw1 + (size_t)p1.x * HID + c * 4);
        const float a0 = __uint_as_float(p0.y);
        const float a1 = __uint_as_float(p1.y);
        acc.x += a0 * v0.x + a1 * v1.x;
        acc.y += a0 * v0.y + a1 * v1.y;
        acc.z += a0 * v0.z + a1 * v1.z;
        acc.w += a0 * v0.w + a1 * v1.w;
    }
    if (e < end) {
        const uint2 p0 = pairs[e];
        const float4 v0 = *(const float4*)(xw1 + (size_t)p0.x * HID + c * 4);
        const float a0 = __uint_as_float(p0.y);
        acc.x += a0 * v0.x; acc.y += a0 * v0.y;
        acc.z += a0 * v0.z; acc.w += a0 * v0.w;
    }
#pragma unroll
    for (int m = 4; m < 64; m <<= 1) {
        acc.x += __shfl_xor(acc.x, m);
        acc.y += __shfl_xor(acc.y, m);
        acc.z += __shfl_xor(acc.z, m);
        acc.w += __shfl_xor(acc.w, m);
    }
    const float4 b1v = ((const float4*)b1)[c];
    float4 hv;
    hv.x = fmaxf(acc.x + b1v.x, 0.f);
    hv.y = fmaxf(acc.y + b1v.y, 0.f);
    hv.z = fmaxf(acc.z + b1v.z, 0.f);
    hv.w = fmaxf(acc.w + b1v.w, 0.f);
    float hh[16];
#pragma unroll
    for (int cc = 0; cc < 4; ++cc) {
        hh[cc * 4 + 0] = __shfl(hv.x, cc);
        hh[cc * 4 + 1] = __shfl(hv.y, cc);
        hh[cc * 4 + 2] = __shfl(hv.z, cc);
        hh[cc * 4 + 3] = __shfl(hv.w, cc);
    }
    const int col = (lane & 7) < OUTD ? (lane & 7) : 0;
    float sacc = 0.f;
#pragma unroll
    for (int j = 0; j < HID; ++j) sacc += hh[j] * w2s[j * OUTD + col];
    if (lane < 8) xw2[(size_t)r * 8 + lane] = (lane < OUTD) ? sacc : 0.f;
}

// ------- gather2: o = sum(a*xw2[src]) + b2 ; fused log_softmax -> out ---------
__global__ __launch_bounds__(256) void gather2_kernel(
    const uint2* __restrict__ pairs, const int* __restrict__ offs,
    const float* __restrict__ xw2, const float* __restrict__ b2,
    float* __restrict__ out, int N)
{
    const int t = threadIdx.x;
    const int lane = t & 63;
    const int r = blockIdx.x * 4 + (t >> 6);
    if (r >= N) return;
    const int g = lane >> 1;
    const int c = lane & 1;
    const int start = offs[r], end = offs[r + 1];
    float4 acc = make_float4(0.f, 0.f, 0.f, 0.f);
    for (int e = start + g; e < end; e += 32) {
        const uint2 p = pairs[e];
        const float4 v = *(const float4*)(xw2 + (size_t)p.x * 8 + c * 4);
        const float a = __uint_as_float(p.y);
        acc.x += a * v.x; acc.y += a * v.y;
        acc.z += a * v.z; acc.w += a * v.w;
    }
#pragma unroll
    for (int m = 2; m < 64; m <<= 1) {
        acc.x += __shfl_xor(acc.x, m);
        acc.y += __shfl_xor(acc.y, m);
        acc.z += __shfl_xor(acc.z, m);
        acc.w += __shfl_xor(acc.w, m);
    }
    float4 x;
    if (c == 0) {
        const float4 b2v = *(const float4*)b2;
        x.x = acc.x + b2v.x; x.y = acc.y + b2v.y;
        x.z = acc.z + b2v.z; x.w = acc.w + b2v.w;
    } else {
        x.x = acc.x + b2[4]; x.y = acc.y + b2[5];
        x.z = acc.z + b2[6]; x.w = -FLT_MAX;
    }
    float mymax = fmaxf(fmaxf(x.x, x.y), x.z);
    if (c == 0) mymax = fmaxf(mymax, x.w);
    const float m = fmaxf(mymax, __shfl_xor(mymax, 1));
    float es = expf(x.x - m) + expf(x.y - m) + expf(x.z - m);
    if (c == 0) es += expf(x.w - m);
    const float s = es + __shfl_xor(es, 1);
    const float lg = logf(s);
    float* op = out + (size_t)r * OUTD;
    if (c == 0) {
        op[0] = x.x - m - lg; op[1] = x.y - m - lg;
        op[2] = x.z - m - lg; op[3] = x.w - m - lg;
    } else {
        op[4] = x.x - m - lg; op[5] = x.y - m - lg;
        op[6] = x.z - m - lg;
    }
}

extern "C" void kernel_launch(void* const* d_in, const int* in_sizes, int n_in,
                              void* d_out, int out_size, void* d_ws, size_t ws_size,
                              hipStream_t stream)
{
    const float* feat  = (const float*)d_in[0];
    const int*   esrc  = (const int*)d_in[1];
    const int*   edst  = (const int*)d_in[2];
    const float* avals = (const float*)d_in[3];
    const float* W1    = (const float*)d_in[4];
    const float* b1    = (const float*)d_in[5];
    const float* W2    = (const float*)d_in[6];
    const float* b2    = (const float*)d_in[7];
    float* out = (float*)d_out;

    const int N = in_sizes[0] / IN_DIM;   // 150000
    const int E = in_sizes[1];            // 4800000
    const int NB = (N + 1023) / 1024;     // 147 (<=256 for scan2)

    // workspace layout
    char* p = (char*)d_ws;
    float* xw1   = (float*)p; p += (size_t)N * HID * sizeof(float);
    float* xw2   = (float*)p; p += (size_t)N * 8 * sizeof(float);
    int*   cnt   = (int*)p;   p += (size_t)N * sizeof(int);
    int*   offs  = (int*)p;   p += (size_t)(N + 1) * sizeof(int);
    int*   cursor= (int*)p;   p += (size_t)N * sizeof(int);
    int*   bsum  = (int*)p;   p += 256 * sizeof(int);
    int*   bbase = (int*)p;   p += 256 * sizeof(int);
    p = (char*)(((uintptr_t)p + 15) & ~(uintptr_t)15);
    uint2* pairs = (uint2*)p;

    hipMemsetAsync(cnt, 0, (size_t)N * sizeof(int), stream);

    gemm1_kernel<<<(N + 255) / 256, 512, 0, stream>>>(feat, W1, xw1, N);

    {
        const int n4 = (E + 3) / 4;
        hist_kernel<<<(n4 + 255) / 256, 256, 0, stream>>>(edst, cnt, E);
    }
    scan1_kernel<<<NB, 256, 0, stream>>>(cnt, offs, bsum, N);
    scan2_kernel<<<1, 256, 0, stream>>>(bsum, bbase, NB);
    scan3_kernel<<<NB, 256, 0, stream>>>(offs, cursor, bbase, N, E);
    {
        const int n4 = (E + 3) / 4;
        fill_kernel<<<(n4 + 255) / 256, 256, 0, stream>>>(esrc, edst, avals, cursor, pairs, E);
    }

    gather1_kernel<<<(N + 3) / 4, 256, 0, stream>>>(pairs, offs, xw1, b1, W2, xw2, N);
    gather2_kernel<<<(N + 3) / 4, 256, 0, stream>>>(pairs, offs, xw2, b2, out, N);
}

// Round 16
// 955.833 us; speedup vs baseline: 1.1680x; 1.0180x over previous
//
#include <hip/hip_runtime.h>
#include <float.h>
#include <stdint.h>

#define IN_DIM 1433
#define HID 16
#define OUTD 7

#define AS1 __attribute__((address_space(1)))
#define AS3 __attribute__((address_space(3)))

// ---------------- GEMM1: xw1[N][16] = feat[N][1433] @ W1[1433][16] -------------
// R13 structure (measured best: 297 us, ~2.9 TB/s effective read).
// Block = 256 rows; wave w owns the 64 rows R = row0 + 4*rc + w (R mod 4 == w),
// so the alignment phase h = (-w)&3 is WAVE-UNIFORM: every row's k-window
// [h + 16*i, ...) starts 16B-aligned -> every global_load_lds width-16 is a
// single aligned line request per lane. W1 indices wave-uniform -> s_load
// (vmcnt-silent compute). Head k<h scalar in prologue. Wave-private 2x4KB LDS
// ring, NO barriers; per-wave s_waitcnt vmcnt(4). LDS: physical 16B-slot p of
// row rc holds logical block p^(rc&3) (pre-swizzled source, rule #21).
__global__ __launch_bounds__(256, 4) void gemm1_kernel(
    const float* __restrict__ feat, const float* __restrict__ W1,
    float* __restrict__ xw1, int N)
{
    __shared__ float xs[4][2][64 * 16];   // [wave][buf][row][16] = 32 KB
    const int t = threadIdx.x;
    const int l = t & 63;                 // lane = row-within-class
    const int w = t >> 6;                 // wave = residue class
    const int row0 = blockIdx.x * 256;
    const int h = __builtin_amdgcn_readfirstlane((4 - w) & 3);
    const long maxBase = (long)N * IN_DIM - 4;

    const int R = row0 + 4 * l + w;       // compute/output row of this thread

    // per-lane source bases for the 4 DMA instrs of a tile
    long src[4];
#pragma unroll
    for (int j = 0; j < 4; ++j) {
        const int rc = j * 16 + (l >> 2);           // row staged by this lane
        const int bs = (l & 3) ^ (rc & 3);          // pre-swizzled 16B block
        src[j] = (long)(row0 + 4 * rc + w) * IN_DIM + h + 4 * bs;
    }

    float acc[16];
#pragma unroll
    for (int j = 0; j < 16; ++j) acc[j] = 0.f;

    // head: k = 0..h-1 (<=3 scalar elements before the aligned window)
    for (int k = 0; k < h; ++k) {
        const float x = (R < N) ? feat[(long)R * IN_DIM + k] : 0.f;
        const float* wr = W1 + k * HID;
#pragma unroll
        for (int j = 0; j < 16; ++j) acc[j] += x * wr[j];
    }
    asm volatile("s_waitcnt vmcnt(0)" ::: "memory");   // drain head loads
    __builtin_amdgcn_sched_barrier(0);

    // stage tile i (16 k's x 64 rows = 4KB): 4 width-16 DMA instrs
    auto stage = [&](int buf, int i) {
#pragma unroll
        for (int j = 0; j < 4; ++j) {
            long e = src[j] + 16 * i;
            if (e > maxBase) e = maxBase;   // tail clamp (OOB rows / last tile)
            __builtin_amdgcn_global_load_lds(
                (const AS1 void*)(feat + e),
                (AS3 void*)(&xs[w][buf][j * 256]), 16, 0, 0);
        }
    };

#define WAITVM(Nimm)                                                         \
    asm volatile("s_waitcnt vmcnt(" #Nimm ")" ::: "memory");                 \
    __builtin_amdgcn_sched_barrier(0);

    const int lx = l & 3;
    // full tile compute: 4 float4-blocks = 16 k's
#define COMPUTE_FULL(buf, i)                                                 \
    {                                                                        \
        const float* xrow = &xs[w][buf][l * 16];                             \
        const int kb0 = h + 16 * (i);                                        \
        _Pragma("unroll")                                                    \
        for (int b = 0; b < 4; ++b) {                                        \
            const float4 xv = *(const float4*)&xrow[((b ^ lx) << 2)];        \
            const float* wk = W1 + (size_t)(kb0 + 4 * b) * HID;              \
            _Pragma("unroll")                                                \
            for (int e = 0; e < 4; ++e) {                                    \
                const float xe = ((const float*)&xv)[e];                     \
                const float4 wA = *(const float4*)(wk + e * HID);            \
                const float4 wB = *(const float4*)(wk + e * HID + 4);        \
                const float4 wC = *(const float4*)(wk + e * HID + 8);        \
                const float4 wD = *(const float4*)(wk + e * HID + 12);       \
                acc[0]  += xe * wA.x; acc[1]  += xe * wA.y;                  \
                acc[2]  += xe * wA.z; acc[3]  += xe * wA.w;                  \
                acc[4]  += xe * wB.x; acc[5]  += xe * wB.y;                  \
                acc[6]  += xe * wB.z; acc[7]  += xe * wB.w;                  \
                acc[8]  += xe * wC.x; acc[9]  += xe * wC.y;                  \
                acc[10] += xe * wC.z; acc[11] += xe * wC.w;                  \
                acc[12] += xe * wD.x; acc[13] += xe * wD.y;                  \
                acc[14] += xe * wD.z; acc[15] += xe * wD.w;                  \
            }                                                                \
        }                                                                    \
    }

    // 90 tiles cover k = h .. 1432 (head covered 0..h-1); last tile kl = 9-h
    stage(0, 0);
    stage(1, 1);
    for (int i = 0; i < 88; ++i) {
        WAITVM(4);                     // tile i resident; tile i+1 in flight
        COMPUTE_FULL(i & 1, i);
        stage(i & 1, i + 2);           // reuse buf after compute read it
    }
    WAITVM(4);
    COMPUTE_FULL(0, 88);
    WAITVM(0);
    {   // tile 89: kl = 9-h valid k's (wave-uniform)
        const int kl = 9 - h;
        const int nb = kl >> 2, tl = kl & 3;
        const float* xrow = &xs[w][1][l * 16];
        const int kb0 = h + 16 * 89;
        for (int b = 0; b < nb; ++b) {
            const float4 xv = *(const float4*)&xrow[((b ^ lx) << 2)];
            const float* wk = W1 + (size_t)(kb0 + 4 * b) * HID;
#pragma unroll
            for (int e = 0; e < 4; ++e) {
                const float xe = ((const float*)&xv)[e];
                const float* wr = wk + e * HID;
#pragma unroll
                for (int j = 0; j < 16; ++j) acc[j] += xe * wr[j];
            }
        }
        for (int kk = nb * 4; kk < nb * 4 + tl; ++kk) {
            const float x = xrow[(((kk >> 2) ^ lx) << 2) | (kk & 3)];
            const float* wr = W1 + (size_t)(kb0 + kk) * HID;
#pragma unroll
            for (int j = 0; j < 16; ++j) acc[j] += x * wr[j];
        }
    }
#undef COMPUTE_FULL
#undef WAITVM

    if (R < N) {
        float4* o = (float4*)(xw1 + (size_t)R * HID);
        o[0] = make_float4(acc[0],  acc[1],  acc[2],  acc[3]);
        o[1] = make_float4(acc[4],  acc[5],  acc[6],  acc[7]);
        o[2] = make_float4(acc[8],  acc[9],  acc[10], acc[11]);
        o[3] = make_float4(acc[12], acc[13], acc[14], acc[15]);
    }
}

// ---------------- CSR build: histogram -> scan -> counting-sort fill ----------
__global__ __launch_bounds__(256) void hist_kernel(
    const int* __restrict__ dst, int* __restrict__ cnt, int E)
{
    const int i4 = blockIdx.x * 256 + threadIdx.x;
    const int e0 = i4 * 4;
    if (e0 + 3 < E) {
        const int4 d = ((const int4*)dst)[i4];
        atomicAdd(&cnt[d.x], 1);
        atomicAdd(&cnt[d.y], 1);
        atomicAdd(&cnt[d.z], 1);
        atomicAdd(&cnt[d.w], 1);
    } else {
        for (int e = e0; e < E; ++e) atomicAdd(&cnt[dst[e]], 1);
    }
}

__global__ __launch_bounds__(256) void scan1_kernel(
    const int* __restrict__ cnt, int* __restrict__ offs,
    int* __restrict__ bsum, int N)
{
    __shared__ int lds[256];
    const int t = threadIdx.x, b = blockIdx.x;
    const int base = b * 1024 + t * 4;
    int c0 = 0, c1 = 0, c2 = 0, c3 = 0;
    if (base + 0 < N) c0 = cnt[base + 0];
    if (base + 1 < N) c1 = cnt[base + 1];
    if (base + 2 < N) c2 = cnt[base + 2];
    if (base + 3 < N) c3 = cnt[base + 3];
    const int s = c0 + c1 + c2 + c3;
    lds[t] = s;
    __syncthreads();
    for (int off = 1; off < 256; off <<= 1) {
        int v = (t >= off) ? lds[t - off] : 0;
        __syncthreads();
        lds[t] += v;
        __syncthreads();
    }
    const int excl = lds[t] - s;
    if (t == 255) bsum[b] = lds[255];
    int run = excl;
    if (base + 0 < N) { offs[base + 0] = run; run += c0; }
    if (base + 1 < N) { offs[base + 1] = run; run += c1; }
    if (base + 2 < N) { offs[base + 2] = run; run += c2; }
    if (base + 3 < N) { offs[base + 3] = run; run += c3; }
}

__global__ __launch_bounds__(256) void scan2_kernel(
    const int* __restrict__ bsum, int* __restrict__ bbase, int NB)
{
    __shared__ int lds[256];
    const int t = threadIdx.x;
    const int v = (t < NB) ? bsum[t] : 0;
    lds[t] = v;
    __syncthreads();
    for (int off = 1; off < 256; off <<= 1) {
        int u = (t >= off) ? lds[t - off] : 0;
        __syncthreads();
        lds[t] += u;
        __syncthreads();
    }
    bbase[t] = lds[t] - v;
}

__global__ __launch_bounds__(256) void scan3_kernel(
    int* __restrict__ offs, int* __restrict__ cursor,
    const int* __restrict__ bbase, int N, int E)
{
    const int t = threadIdx.x, b = blockIdx.x;
    const int add = bbase[b];
    const int base = b * 1024 + t * 4;
#pragma unroll
    for (int i = 0; i < 4; ++i) {
        const int idx = base + i;
        if (idx < N) {
            const int v = offs[idx] + add;
            offs[idx] = v;
            cursor[idx] = v;
        }
    }
    if (b == 0 && t == 0) offs[N] = E;
}

__global__ __launch_bounds__(256) void fill_kernel(
    const int* __restrict__ src, const int* __restrict__ dst,
    const float* __restrict__ a, int* __restrict__ cursor,
    uint2* __restrict__ pairs, int E)
{
    const int i4 = blockIdx.x * 256 + threadIdx.x;
    const int e0 = i4 * 4;
    if (e0 + 3 < E) {
        const int4   s4 = ((const int4*)src)[i4];
        const int4   d4 = ((const int4*)dst)[i4];
        const float4 a4 = ((const float4*)a)[i4];
        int p0 = atomicAdd(&cursor[d4.x], 1);
        pairs[p0] = make_uint2((unsigned)s4.x, __float_as_uint(a4.x));
        int p1 = atomicAdd(&cursor[d4.y], 1);
        pairs[p1] = make_uint2((unsigned)s4.y, __float_as_uint(a4.y));
        int p2 = atomicAdd(&cursor[d4.z], 1);
        pairs[p2] = make_uint2((unsigned)s4.z, __float_as_uint(a4.z));
        int p3 = atomicAdd(&cursor[d4.w], 1);
        pairs[p3] = make_uint2((unsigned)s4.w, __float_as_uint(a4.w));
    } else {
        for (int e = e0; e < E; ++e) {
            const int pos = atomicAdd(&cursor[dst[e]], 1);
            pairs[pos] = make_uint2((unsigned)src[e], __float_as_uint(a[e]));
        }
    }
}

// ------- gather1: agg = sum(a*xw1[src]) ; fused h=relu(agg+b1); xw2 = h@W2 ----
__global__ __launch_bounds__(256) void gather1_kernel(
    const uint2* __restrict__ pairs, const int* __restrict__ offs,
    const float* __restrict__ xw1, const float* __restrict__ b1,
    const float* __restrict__ W2, float* __restrict__ xw2, int N)
{
    __shared__ float w2s[HID * OUTD];
    const int t = threadIdx.x;
    if (t < HID * OUTD) w2s[t] = W2[t];
    __syncthreads();
    const int lane = t & 63;
    const int r = blockIdx.x * 4 + (t >> 6);
    if (r >= N) return;
    const int g = lane >> 2;
    const int c = lane & 3;
    const int start = offs[r], end = offs[r + 1];
    float4 acc = make_float4(0.f, 0.f, 0.f, 0.f);
    int e = start + g;
    for (; e + 16 < end; e += 32) {
        const uint2 p0 = pairs[e];
        const uint2 p1 = pairs[e + 16];
        const float4 v0 = *(const float4*)(xw1 + (size_t)p0.x * HID + c * 4);
        const float4 v1 = *(const float4*)(xw1 + (size_t)p1.x * HID + c * 4);
        const float a0 = __uint_as_float(p0.y);
        const float a1 = __uint_as_float(p1.y);
        acc.x += a0 * v0.x + a1 * v1.x;
        acc.y += a0 * v0.y + a1 * v1.y;
        acc.z += a0 * v0.z + a1 * v1.z;
        acc.w += a0 * v0.w + a1 * v1.w;
    }
    if (e < end) {
        const uint2 p0 = pairs[e];
        const float4 v0 = *(const float4*)(xw1 + (size_t)p0.x * HID + c * 4);
        const float a0 = __uint_as_float(p0.y);
        acc.x += a0 * v0.x; acc.y += a0 * v0.y;
        acc.z += a0 * v0.z; acc.w += a0 * v0.w;
    }
#pragma unroll
    for (int m = 4; m < 64; m <<= 1) {
        acc.x += __shfl_xor(acc.x, m);
        acc.y += __shfl_xor(acc.y, m);
        acc.z += __shfl_xor(acc.z, m);
        acc.w += __shfl_xor(acc.w, m);
    }
    const float4 b1v = ((const float4*)b1)[c];
    float4 hv;
    hv.x = fmaxf(acc.x + b1v.x, 0.f);
    hv.y = fmaxf(acc.y + b1v.y, 0.f);
    hv.z = fmaxf(acc.z + b1v.z, 0.f);
    hv.w = fmaxf(acc.w + b1v.w, 0.f);
    float hh[16];
#pragma unroll
    for (int cc = 0; cc < 4; ++cc) {
        hh[cc * 4 + 0] = __shfl(hv.x, cc);
        hh[cc * 4 + 1] = __shfl(hv.y, cc);
        hh[cc * 4 + 2] = __shfl(hv.z, cc);
        hh[cc * 4 + 3] = __shfl(hv.w, cc);
    }
    const int col = (lane & 7) < OUTD ? (lane & 7) : 0;
    float sacc = 0.f;
#pragma unroll
    for (int j = 0; j < HID; ++j) sacc += hh[j] * w2s[j * OUTD + col];
    if (lane < 8) xw2[(size_t)r * 8 + lane] = (lane < OUTD) ? sacc : 0.f;
}

// ------- gather2: o = sum(a*xw2[src]) + b2 ; fused log_softmax -> out ---------
__global__ __launch_bounds__(256) void gather2_kernel(
    const uint2* __restrict__ pairs, const int* __restrict__ offs,
    const float* __restrict__ xw2, const float* __restrict__ b2,
    float* __restrict__ out, int N)
{
    const int t = threadIdx.x;
    const int lane = t & 63;
    const int r = blockIdx.x * 4 + (t >> 6);
    if (r >= N) return;
    const int g = lane >> 1;
    const int c = lane & 1;
    const int start = offs[r], end = offs[r + 1];
    float4 acc = make_float4(0.f, 0.f, 0.f, 0.f);
    for (int e = start + g; e < end; e += 32) {
        const uint2 p = pairs[e];
        const float4 v = *(const float4*)(xw2 + (size_t)p.x * 8 + c * 4);
        const float a = __uint_as_float(p.y);
        acc.x += a * v.x; acc.y += a * v.y;
        acc.z += a * v.z; acc.w += a * v.w;
    }
#pragma unroll
    for (int m = 2; m < 64; m <<= 1) {
        acc.x += __shfl_xor(acc.x, m);
        acc.y += __shfl_xor(acc.y, m);
        acc.z += __shfl_xor(acc.z, m);
        acc.w += __shfl_xor(acc.w, m);
    }
    float4 x;
    if (c == 0) {
        const float4 b2v = *(const float4*)b2;
        x.x = acc.x + b2v.x; x.y = acc.y + b2v.y;
        x.z = acc.z + b2v.z; x.w = acc.w + b2v.w;
    } else {
        x.x = acc.x + b2[4]; x.y = acc.y + b2[5];
        x.z = acc.z + b2[6]; x.w = -FLT_MAX;
    }
    float mymax = fmaxf(fmaxf(x.x, x.y), x.z);
    if (c == 0) mymax = fmaxf(mymax, x.w);
    const float m = fmaxf(mymax, __shfl_xor(mymax, 1));
    float es = expf(x.x - m) + expf(x.y - m) + expf(x.z - m);
    if (c == 0) es += expf(x.w - m);
    const float s = es + __shfl_xor(es, 1);
    const float lg = logf(s);
    float* op = out + (size_t)r * OUTD;
    if (c == 0) {
        op[0] = x.x - m - lg; op[1] = x.y - m - lg;
        op[2] = x.z - m - lg; op[3] = x.w - m - lg;
    } else {
        op[4] = x.x - m - lg; op[5] = x.y - m - lg;
        op[6] = x.z - m - lg;
    }
}

extern "C" void kernel_launch(void* const* d_in, const int* in_sizes, int n_in,
                              void* d_out, int out_size, void* d_ws, size_t ws_size,
                              hipStream_t stream)
{
    const float* feat  = (const float*)d_in[0];
    const int*   esrc  = (const int*)d_in[1];
    const int*   edst  = (const int*)d_in[2];
    const float* avals = (const float*)d_in[3];
    const float* W1    = (const float*)d_in[4];
    const float* b1    = (const float*)d_in[5];
    const float* W2    = (const float*)d_in[6];
    const float* b2    = (const float*)d_in[7];
    float* out = (float*)d_out;

    const int N = in_sizes[0] / IN_DIM;   // 150000
    const int E = in_sizes[1];            // 4800000
    const int NB = (N + 1023) / 1024;     // 147 (<=256 for scan2)

    // workspace layout
    char* p = (char*)d_ws;
    float* xw1   = (float*)p; p += (size_t)N * HID * sizeof(float);
    float* xw2   = (float*)p; p += (size_t)N * 8 * sizeof(float);
    int*   cnt   = (int*)p;   p += (size_t)N * sizeof(int);
    int*   offs  = (int*)p;   p += (size_t)(N + 1) * sizeof(int);
    int*   cursor= (int*)p;   p += (size_t)N * sizeof(int);
    int*   bsum  = (int*)p;   p += 256 * sizeof(int);
    int*   bbase = (int*)p;   p += 256 * sizeof(int);
    p = (char*)(((uintptr_t)p + 15) & ~(uintptr_t)15);
    uint2* pairs = (uint2*)p;

    hipMemsetAsync(cnt, 0, (size_t)N * sizeof(int), stream);

    gemm1_kernel<<<(N + 255) / 256, 256, 0, stream>>>(feat, W1, xw1, N);

    {
        const int n4 = (E + 3) / 4;
        hist_kernel<<<(n4 + 255) / 256, 256, 0, stream>>>(edst, cnt, E);
    }
    scan1_kernel<<<NB, 256, 0, stream>>>(cnt, offs, bsum, N);
    scan2_kernel<<<1, 256, 0, stream>>>(bsum, bbase, NB);
    scan3_kernel<<<NB, 256, 0, stream>>>(offs, cursor, bbase, N, E);
    {
        const int n4 = (E + 3) / 4;
        fill_kernel<<<(n4 + 255) / 256, 256, 0, stream>>>(esrc, edst, avals, cursor, pairs, E);
    }

    gather1_kernel<<<(N + 3) / 4, 256, 0, stream>>>(pairs, offs, xw1, b1, W2, xw2, N);
    gather2_kernel<<<(N + 3) / 4, 256, 0, stream>>>(pairs, offs, xw2, b2, out, N);
}